// Round 8
// baseline (219.585 us; speedup 1.0000x reference)
//
#include <hip/hip_runtime.h>

#define DIM 64

// async global->LDS, 16B per lane; LDS dest = wave-uniform base + lane*16
#define GLD_LDS(gp, lp)                                                        \
    __builtin_amdgcn_global_load_lds(                                          \
        (const __attribute__((address_space(1))) unsigned int*)(gp),           \
        (__attribute__((address_space(3))) unsigned int*)(lp), 16, 0, 0)

// ---- parallel counting-sort pipeline: zero(memset) -> hist -> scan -> scatter

__global__ __launch_bounds__(256) void k_hist(const int* __restrict__ m2,
                                              int* __restrict__ cnt, int N) {
    const int i = blockIdx.x * 256 + threadIdx.x;
    if (i < N) atomicAdd(&cnt[m2[i] >> 7], 1);
}

__global__ __launch_bounds__(256) void k_scan(int* __restrict__ cnt, int nbuck) {
    __shared__ int s[256];
    const int tid  = threadIdx.x;
    const int base = tid * 10;
    int loc[10];
    int sum = 0;
    #pragma unroll
    for (int u = 0; u < 10; ++u) {
        const int idx = base + u;
        const int v = (idx < nbuck) ? cnt[idx] : 0;
        loc[u] = sum;
        sum += v;
    }
    s[tid] = sum;
    __syncthreads();
    for (int off = 1; off < 256; off <<= 1) {
        const int v = (tid >= off) ? s[tid - off] : 0;
        __syncthreads();
        s[tid] += v;
        __syncthreads();
    }
    const int excl = (tid > 0) ? s[tid - 1] : 0;
    #pragma unroll
    for (int u = 0; u < 10; ++u) {
        const int idx = base + u;
        if (idx < nbuck) cnt[idx] = excl + loc[u];
    }
}

__global__ __launch_bounds__(256) void k_scatter(const int* __restrict__ m1,
                                                 const int* __restrict__ m2,
                                                 int* __restrict__ cnt,
                                                 int* __restrict__ i1s,
                                                 int* __restrict__ i2s, int N) {
    const int i = blockIdx.x * 256 + threadIdx.x;
    if (i < N) {
        const int v2  = m2[i];
        const int pos = atomicAdd(&cnt[v2 >> 7], 1);
        i1s[pos] = m1[i];
        i2s[pos] = v2;
    }
}

// =====================================================================
// Main V3: async-LDS staging. R6/R7 proved register-held MLP is capped
// at ~6 loads/wave by the allocator (VGPR=36) and divergent guards
// fragment scheduling regions. global_load_lds has NO result VGPRs ->
// all 12 b-row loads per lane issue back-to-back, one vmcnt(0) drains
// them. Each lane reads back exactly the 16B it staged (HW dest =
// wave-uniform base + lane*16) -> lane-local, conflict-free, and no
// extra barrier (waves consume only their own chunks).
// =====================================================================
__global__ __launch_bounds__(256) void pixel_ap_main(
    const float* __restrict__ d1, const float* __restrict__ d2,
    const float* __restrict__ qw, const float* __restrict__ qb,
    const int* __restrict__ offs,
    const int* __restrict__ i1s, const int* __restrict__ i2s,
    float* __restrict__ partial, int P, int NEG, int NQ2, int N)
{
    const int tid = threadIdx.x;
    const int nq  = NQ2 >> 1;
    const int M   = NEG + 1;          // 81 scores per match

    __shared__ float  s_scores[2][96];
    __shared__ float4 s_stage[2][3][4][2][64];  // [match][t][wave][half][lane], 48 KB

    // XCD-aware contiguous slice over pair-index space (block b -> XCD b%8)
    const int b    = blockIdx.x;
    const int per  = gridDim.x >> 3;                // gridDim = 8*per
    const int pr   = (b & 7) * per + (b >> 3);      // pair index
    const int posA = 2 * pr;
    const int posB = posA + 1;
    if (posA >= N) return;                          // block-uniform
    const bool hasB = (posB < N);

    const int g    = tid >> 3;        // group 0..31
    const int sl   = tid & 7;         // 8 lanes x 32 B = 256 B per row
    const int w    = tid >> 6;        // wave id
    const int lane = tid & 63;

    const int i1A = i1s[posA];
    const int i2A = i2s[posA];
    const int i1B = hasB ? i1s[posB] : i1A;
    const int i2B = hasB ? i2s[posB] : i2A;

    // row indices for 3 scores per match (unconditional: clamp offs index
    // for j in [81,95] -> straight-line staging, garbage scores unread)
    int rA[3], rB[3];
    #pragma unroll
    for (int t = 0; t < 3; ++t) {
        const int j = g + 32 * t;
        const int o = (j == 0) ? 0 : offs[min(j, M - 1) - 1];
        rA[t] = (j == 0) ? i2A : min(i2A + o, P - 1);
        rB[t] = (j == 0) ? i2B : min(i2B + o, P - 1);
    }

    // issue ALL 12 async b-row loads (no VGPR results -> true MLP=12)
    #pragma unroll
    for (int t = 0; t < 3; ++t) {
        const float* pA = d2 + (size_t)rA[t] * DIM + 8 * sl;
        GLD_LDS(pA,     &s_stage[0][t][w][0][0]);
        GLD_LDS(pA + 4, &s_stage[0][t][w][1][0]);
        const float* pB = d2 + (size_t)rB[t] * DIM + 8 * sl;
        GLD_LDS(pB,     &s_stage[1][t][w][0][0]);
        GLD_LDS(pB + 4, &s_stage[1][t][w][1][0]);
    }

    // a fragments (regular loads; drained by the same vmcnt)
    const float* aA = d1 + (size_t)i1A * DIM + 8 * sl;
    const float* aB = d1 + (size_t)i1B * DIM + 8 * sl;
    const float4 a0A = ((const float4*)aA)[0];
    const float4 a1A = ((const float4*)aA)[1];
    const float4 a0B = ((const float4*)aB)[0];
    const float4 a1B = ((const float4*)aB)[1];

    asm volatile("s_waitcnt vmcnt(0)" ::: "memory");
    __builtin_amdgcn_sched_barrier(0);

    // consume: each lane reads back exactly its own staged 16B chunks
    #pragma unroll
    for (int t = 0; t < 3; ++t) {
        const int j = g + 32 * t;
        const float4 b0A = s_stage[0][t][w][0][lane];
        const float4 b1A = s_stage[0][t][w][1][lane];
        const float4 b0B = s_stage[1][t][w][0][lane];
        const float4 b1B = s_stage[1][t][w][1][lane];
        float sA = b0A.x * a0A.x + b0A.y * a0A.y + b0A.z * a0A.z + b0A.w * a0A.w
                 + b1A.x * a1A.x + b1A.y * a1A.y + b1A.z * a1A.z + b1A.w * a1A.w;
        float sB = b0B.x * a0B.x + b0B.y * a0B.y + b0B.z * a0B.z + b0B.w * a0B.w
                 + b1B.x * a1B.x + b1B.y * a1B.y + b1B.z * a1B.z + b1B.w * a1B.w;
        sA += __shfl_xor(sA, 1);
        sA += __shfl_xor(sA, 2);
        sA += __shfl_xor(sA, 4);
        sB += __shfl_xor(sB, 1);
        sB += __shfl_xor(sB, 2);
        sB += __shfl_xor(sB, 4);
        if (sl == 0) {
            s_scores[0][j] = sA;
            s_scores[1][j] = sB;
        }
    }
    __syncthreads();
    if (w >= 2) return;               // waves 2,3 retire
    if (w == 1 && !hasB) return;

    // ---- hat-basis AP epilogue, one wave per match ----
    const float a_scale = qw[nq];               // +a
    const float amn     = qb[nq - 1] - 1.0f;    // a*mn
    const float ulim    = (float)(nq - 1);

    const float xp = s_scores[w][0];
    const float up = fminf(fmaxf(a_scale * xp - amn, 0.0f), ulim);
    const float ip = floorf(up);
    const float fp = up - ip;

    float n1 = 0.0f, n2 = 0.0f;
    {
        const float x  = s_scores[w][lane];
        const float u  = fminf(fmaxf(a_scale * x - amn, 0.0f), ulim);
        const float fi = floorf(u);
        const float f  = u - fi;
        n2 += (fi >= ip)        ? 1.0f : ((fi == ip - 1.0f) ? f : 0.0f);
        n1 += (fi >= ip + 1.0f) ? 1.0f : ((fi == ip)        ? f : 0.0f);
    }
    if (lane + 64 < M) {
        const float x  = s_scores[w][lane + 64];
        const float u  = fminf(fmaxf(a_scale * x - amn, 0.0f), ulim);
        const float fi = floorf(u);
        const float f  = u - fi;
        n2 += (fi >= ip)        ? 1.0f : ((fi == ip - 1.0f) ? f : 0.0f);
        n1 += (fi >= ip + 1.0f) ? 1.0f : ((fi == ip)        ? f : 0.0f);
    }
    #pragma unroll
    for (int off = 32; off >= 1; off >>= 1) {
        n1 += __shfl_xor(n1, off);
        n2 += __shfl_xor(n2, off);
    }
    if (lane == 0) {
        const float ap = fp * fp / (1e-16f + n1) + (1.0f - fp) / (1e-16f + n2);
        partial[posA + w] = 1.0f - ap;
    }
}

// ---- single-block final reduction ----
__global__ __launch_bounds__(1024) void k_reduce(const float* __restrict__ partial,
                                                 float* __restrict__ out, int N)
{
    float s = 0.0f;
    for (int i = threadIdx.x; i < N; i += 1024) s += partial[i];
    #pragma unroll
    for (int off = 32; off >= 1; off >>= 1) s += __shfl_xor(s, off);
    __shared__ float sw[16];
    if ((threadIdx.x & 63) == 0) sw[threadIdx.x >> 6] = s;
    __syncthreads();
    if (threadIdx.x == 0) {
        float t = 0.0f;
        #pragma unroll
        for (int w = 0; w < 16; ++w) t += sw[w];
        out[0] = t / (float)N;
    }
}

extern "C" void kernel_launch(void* const* d_in, const int* in_sizes, int n_in,
                              void* d_out, int out_size, void* d_ws, size_t ws_size,
                              hipStream_t stream) {
    const float* d1   = (const float*)d_in[0];
    const float* d2   = (const float*)d_in[1];
    const float* qw   = (const float*)d_in[2];
    const float* qb   = (const float*)d_in[3];
    const int*   m1   = (const int*)d_in[4];
    const int*   m2   = (const int*)d_in[5];
    const int*   offs = (const int*)d_in[6];

    const int N     = in_sizes[4];
    const int P     = in_sizes[0] / DIM;
    const int NEG   = in_sizes[6];
    const int NQ2   = in_sizes[2];
    const int nbuck = (P + 127) >> 7;

    int*   cnt     = (int*)d_ws;
    int*   i1s     = cnt + nbuck;
    int*   i2s     = i1s + N;
    float* partial = (float*)(i2s + N);

    const int nblk = (N + 255) / 256;

    hipMemsetAsync(cnt, 0, (size_t)nbuck * sizeof(int), stream);
    k_hist   <<<nblk, 256, 0, stream>>>(m2, cnt, N);
    k_scan   <<<1, 256, 0, stream>>>(cnt, nbuck);
    k_scatter<<<nblk, 256, 0, stream>>>(m1, m2, cnt, i1s, i2s, N);

    const int npair = (N + 1) / 2;
    const int per   = (npair + 7) / 8;
    pixel_ap_main<<<8 * per, 256, 0, stream>>>(d1, d2, qw, qb, offs, i1s, i2s,
                                               partial, P, NEG, NQ2, N);

    k_reduce<<<1, 1024, 0, stream>>>(partial, (float*)d_out, N);
}

// Round 9
// 200.759 us; speedup vs baseline: 1.0938x; 1.0938x over previous
//
#include <hip/hip_runtime.h>

#define DIM 64

// ---- parallel counting-sort pipeline: zero(memset) -> hist -> scan -> scatter

__global__ __launch_bounds__(256) void k_hist(const int* __restrict__ m2,
                                              int* __restrict__ cnt, int N) {
    const int i = blockIdx.x * 256 + threadIdx.x;
    if (i < N) atomicAdd(&cnt[m2[i] >> 7], 1);
}

__global__ __launch_bounds__(256) void k_scan(int* __restrict__ cnt, int nbuck) {
    __shared__ int s[256];
    const int tid  = threadIdx.x;
    const int base = tid * 10;
    int loc[10];
    int sum = 0;
    #pragma unroll
    for (int u = 0; u < 10; ++u) {
        const int idx = base + u;
        const int v = (idx < nbuck) ? cnt[idx] : 0;
        loc[u] = sum;
        sum += v;
    }
    s[tid] = sum;
    __syncthreads();
    for (int off = 1; off < 256; off <<= 1) {
        const int v = (tid >= off) ? s[tid - off] : 0;
        __syncthreads();
        s[tid] += v;
        __syncthreads();
    }
    const int excl = (tid > 0) ? s[tid - 1] : 0;
    #pragma unroll
    for (int u = 0; u < 10; ++u) {
        const int idx = base + u;
        if (idx < nbuck) cnt[idx] = excl + loc[u];
    }
}

__global__ __launch_bounds__(256) void k_scatter(const int* __restrict__ m1,
                                                 const int* __restrict__ m2,
                                                 int* __restrict__ cnt,
                                                 int* __restrict__ i1s,
                                                 int* __restrict__ i2s, int N) {
    const int i = blockIdx.x * 256 + threadIdx.x;
    if (i < N) {
        const int v2  = m2[i];
        const int pos = atomicAdd(&cnt[v2 >> 7], 1);
        i1s[pos] = m1[i];
        i2s[pos] = v2;
    }
}

// =====================================================================
// Main V4: PERSISTENT blocks. R0's 10000 short blocks averaged only 58%
// occupancy (block churn: repeated prologues + ramp/drain); R8 showed
// speed tracks resident waves x independent progress points. Here:
// exactly-resident grid (8 blocks/CU, VGPR<=64, tiny LDS), each block
// grid-strides over ~5 sorted pairs with the R0-proven inner body.
// Double-buffered s_scores -> ONE barrier per pair (epilogue(it) happens
// before barrier(it+1) which precedes any fill(it+2) into same buffer).
// offs/quantizer constants hoisted: paid 2048x instead of 10000x.
// =====================================================================
__global__ __launch_bounds__(256) void pixel_ap_main(
    const float* __restrict__ d1, const float* __restrict__ d2,
    const float* __restrict__ qw, const float* __restrict__ qb,
    const int* __restrict__ offs,
    const int* __restrict__ i1s, const int* __restrict__ i2s,
    float* __restrict__ partial, int P, int NEG, int NQ2, int N)
{
    const int tid = threadIdx.x;
    const int nq  = NQ2 >> 1;
    const int M   = NEG + 1;          // 81 scores per match

    __shared__ float s_scores[2][2][96];   // [it&1][match A/B][j]

    const int b     = blockIdx.x;
    const int nG    = gridDim.x;           // multiple of 8
    const int npair = (N + 1) >> 1;
    const int per   = (npair + 7) >> 3;    // pairs per XCD slice
    const int pbeg  = (b & 7) * per;       // slice = b & 7 (XCD-contiguous)
    const int pend  = (pbeg + per < npair) ? (pbeg + per) : npair;
    const int step  = nG >> 3;             // blocks per slice

    const int g    = tid >> 3;        // group 0..31
    const int sl   = tid & 7;         // 8 lanes x 32 B = 256 B per row
    const int w    = tid >> 6;        // wave id
    const int lane = tid & 63;

    // hoisted invariants (paid once per block, not once per pair)
    int oj[3];
    #pragma unroll
    for (int t = 0; t < 3; ++t) {
        const int j = g + 32 * t;
        oj[t] = (j == 0) ? 0 : ((j < M) ? offs[j - 1] : 0);
    }
    const float a_scale = qw[nq];               // +a
    const float amn     = qb[nq - 1] - 1.0f;    // a*mn
    const float ulim    = (float)(nq - 1);

    int it = 0;
    for (int pr = pbeg + (b >> 3); pr < pend; pr += step, ++it) {
        float (*sc)[96] = s_scores[it & 1];
        const int posA = 2 * pr;
        const int posB = posA + 1;
        const bool hasB = (posB < N);          // block-uniform

        const int i1A = i1s[posA];
        const int i2A = i2s[posA];
        const int i1B = hasB ? i1s[posB] : i1A;
        const int i2B = hasB ? i2s[posB] : i2A;

        // a fragments for both matches
        const float* aA = d1 + (size_t)i1A * DIM + 8 * sl;
        const float* aB = d1 + (size_t)i1B * DIM + 8 * sl;
        const float4 a0A = ((const float4*)aA)[0];
        const float4 a1A = ((const float4*)aA)[1];
        const float4 a0B = ((const float4*)aB)[0];
        const float4 a1B = ((const float4*)aB)[1];

        // row indices for 3 scores per match
        int rA[3], rB[3];
        #pragma unroll
        for (int t = 0; t < 3; ++t) {
            const int j = g + 32 * t;
            if (j < M) {
                rA[t] = (j == 0) ? i2A : min(i2A + oj[t], P - 1);
                rB[t] = (j == 0) ? i2B : min(i2B + oj[t], P - 1);
            }
        }

        // all 12 b-loads issued before any math
        float4 b0A[3], b1A[3], b0B[3], b1B[3];
        #pragma unroll
        for (int t = 0; t < 3; ++t) {
            const int j = g + 32 * t;
            if (j < M) {
                const float* pA = d2 + (size_t)rA[t] * DIM + 8 * sl;
                b0A[t] = ((const float4*)pA)[0];
                b1A[t] = ((const float4*)pA)[1];
                const float* pB = d2 + (size_t)rB[t] * DIM + 8 * sl;
                b0B[t] = ((const float4*)pB)[0];
                b1B[t] = ((const float4*)pB)[1];
            }
        }
        #pragma unroll
        for (int t = 0; t < 3; ++t) {
            const int j = g + 32 * t;
            if (j < M) {
                float sA = b0A[t].x * a0A.x + b0A[t].y * a0A.y + b0A[t].z * a0A.z + b0A[t].w * a0A.w
                         + b1A[t].x * a1A.x + b1A[t].y * a1A.y + b1A[t].z * a1A.z + b1A[t].w * a1A.w;
                float sB = b0B[t].x * a0B.x + b0B[t].y * a0B.y + b0B[t].z * a0B.z + b0B[t].w * a0B.w
                         + b1B[t].x * a1B.x + b1B[t].y * a1B.y + b1B[t].z * a1B.z + b1B[t].w * a1B.w;
                sA += __shfl_xor(sA, 1);
                sA += __shfl_xor(sA, 2);
                sA += __shfl_xor(sA, 4);
                sB += __shfl_xor(sB, 1);
                sB += __shfl_xor(sB, 2);
                sB += __shfl_xor(sB, 4);
                if (sl == 0) {
                    sc[0][j] = sA;
                    sc[1][j] = sB;
                }
            }
        }
        __syncthreads();

        // ---- hat-basis AP epilogue, waves 0/1 (others proceed to next fill) ----
        if (w < 2 && (w == 0 || hasB)) {
            const float xp = sc[w][0];
            const float up = fminf(fmaxf(a_scale * xp - amn, 0.0f), ulim);
            const float ip = floorf(up);
            const float fp = up - ip;

            float n1 = 0.0f, n2 = 0.0f;
            {
                const float x  = sc[w][lane];
                const float u  = fminf(fmaxf(a_scale * x - amn, 0.0f), ulim);
                const float fi = floorf(u);
                const float f  = u - fi;
                n2 += (fi >= ip)        ? 1.0f : ((fi == ip - 1.0f) ? f : 0.0f);
                n1 += (fi >= ip + 1.0f) ? 1.0f : ((fi == ip)        ? f : 0.0f);
            }
            if (lane + 64 < M) {
                const float x  = sc[w][lane + 64];
                const float u  = fminf(fmaxf(a_scale * x - amn, 0.0f), ulim);
                const float fi = floorf(u);
                const float f  = u - fi;
                n2 += (fi >= ip)        ? 1.0f : ((fi == ip - 1.0f) ? f : 0.0f);
                n1 += (fi >= ip + 1.0f) ? 1.0f : ((fi == ip)        ? f : 0.0f);
            }
            #pragma unroll
            for (int off = 32; off >= 1; off >>= 1) {
                n1 += __shfl_xor(n1, off);
                n2 += __shfl_xor(n2, off);
            }
            if (lane == 0) {
                const float ap = fp * fp / (1e-16f + n1) + (1.0f - fp) / (1e-16f + n2);
                partial[posA + w] = 1.0f - ap;
            }
        }
    }
}

// ---- single-block final reduction ----
__global__ __launch_bounds__(1024) void k_reduce(const float* __restrict__ partial,
                                                 float* __restrict__ out, int N)
{
    float s = 0.0f;
    for (int i = threadIdx.x; i < N; i += 1024) s += partial[i];
    #pragma unroll
    for (int off = 32; off >= 1; off >>= 1) s += __shfl_xor(s, off);
    __shared__ float sw[16];
    if ((threadIdx.x & 63) == 0) sw[threadIdx.x >> 6] = s;
    __syncthreads();
    if (threadIdx.x == 0) {
        float t = 0.0f;
        #pragma unroll
        for (int w = 0; w < 16; ++w) t += sw[w];
        out[0] = t / (float)N;
    }
}

extern "C" void kernel_launch(void* const* d_in, const int* in_sizes, int n_in,
                              void* d_out, int out_size, void* d_ws, size_t ws_size,
                              hipStream_t stream) {
    const float* d1   = (const float*)d_in[0];
    const float* d2   = (const float*)d_in[1];
    const float* qw   = (const float*)d_in[2];
    const float* qb   = (const float*)d_in[3];
    const int*   m1   = (const int*)d_in[4];
    const int*   m2   = (const int*)d_in[5];
    const int*   offs = (const int*)d_in[6];

    const int N     = in_sizes[4];
    const int P     = in_sizes[0] / DIM;
    const int NEG   = in_sizes[6];
    const int NQ2   = in_sizes[2];
    const int nbuck = (P + 127) >> 7;

    int*   cnt     = (int*)d_ws;
    int*   i1s     = cnt + nbuck;
    int*   i2s     = i1s + N;
    float* partial = (float*)(i2s + N);

    const int nblk = (N + 255) / 256;

    hipMemsetAsync(cnt, 0, (size_t)nbuck * sizeof(int), stream);
    k_hist   <<<nblk, 256, 0, stream>>>(m2, cnt, N);
    k_scan   <<<1, 256, 0, stream>>>(cnt, nbuck);
    k_scatter<<<nblk, 256, 0, stream>>>(m1, m2, cnt, i1s, i2s, N);

    // persistent grid: 8 blocks/CU x 256 CUs = 2048 (VGPR<=64, tiny LDS
    // -> all co-resident); cap by pair count, keep multiple of 8.
    const int npair = (N + 1) / 2;
    int nmain = 2048;
    if (nmain > npair) nmain = ((npair + 7) / 8) * 8;
    pixel_ap_main<<<nmain, 256, 0, stream>>>(d1, d2, qw, qb, offs, i1s, i2s,
                                             partial, P, NEG, NQ2, N);

    k_reduce<<<1, 1024, 0, stream>>>(partial, (float*)d_out, N);
}